// Round 7
// baseline (245.065 us; speedup 1.0000x reference)
//
#include <hip/hip_runtime.h>
#include <hip/hip_bf16.h>
#include <math.h>

#define NV 64
#define ND 64
#define NTOK 8192
#define LN_EPS 1e-5f

typedef __attribute__((ext_vector_type(8))) short s8v;    // 8 bf16 = 4 VGPR
typedef __attribute__((ext_vector_type(4))) float f4v;    // MFMA C/D
typedef __attribute__((ext_vector_type(4))) int   i4v;

__device__ __forceinline__ float sigm_f(float x) { return 1.f / (1.f + __expf(-x)); }
__device__ __forceinline__ float elu_f(float x)  { return x > 0.f ? x : (__expf(x) - 1.f); }

__device__ __forceinline__ float bf16_to_f(unsigned short s) {
    union { unsigned int u; float f; } c; c.u = ((unsigned int)s) << 16;
    return c.f;
}
// 1-op round-to-nearest (ties away): fine numerically, 3 ops cheaper than RNE
__device__ __forceinline__ unsigned short bf16_rn(float f) {
    union { float f; unsigned int u; } c; c.f = f;
    return (unsigned short)((c.u + 0x8000u) >> 16);
}

// ---------------- Prepack: all weight transposes via LDS tiles (coalesced R+W)
// blocks 0..63:   v = b: w2b/wgb[v][e][d] <- W2/Wg[v][d][e]
// blocks 64..191: wct[n][k] = concat(Wn1,Wns)[k][n], 64x64 k-tiles
__global__ __launch_bounds__(256) void vsn_prepack(
    const float* __restrict__ W2, const float* __restrict__ Wg,
    const float* __restrict__ Wn1, const float* __restrict__ Wns,
    short* __restrict__ w2b, short* __restrict__ wgb,
    __hip_bfloat16* __restrict__ wct)
{
    __shared__ float T[64][65];
    const int b = blockIdx.x, t = threadIdx.x;

    if (b < 64) {
        const float* src = W2 + (size_t)b * 4096;
        short* dst = w2b + (size_t)b * 4096;
        #pragma unroll
        for (int pass = 0; pass < 2; ++pass) {
            #pragma unroll
            for (int i = 0; i < 16; ++i) {
                int id = i * 256 + t;
                T[id & 63][id >> 6] = src[id];      // read [d][e] coalesced
            }
            __syncthreads();
            #pragma unroll
            for (int i = 0; i < 16; ++i) {
                int id = i * 256 + t;               // ordered [e][d]
                dst[id] = (short)bf16_rn(T[id >> 6][id & 63]);
            }
            __syncthreads();
            src = Wg + (size_t)b * 4096;
            dst = wgb + (size_t)b * 4096;
        }
    } else {
        int tb = b - 64;                 // 0..127
        int half = tb >> 6, kt = tb & 63;
        const float* src = (half == 0 ? Wn1 : Wns) + (size_t)(kt * 64) * 64;
        #pragma unroll
        for (int i = 0; i < 16; ++i) {
            int id = i * 256 + t;        // r = id>>6, n = id&63  (coalesced over n)
            T[id & 63][id >> 6] = src[id];
        }
        __syncthreads();
        #pragma unroll
        for (int i = 0; i < 16; ++i) {
            int id = i * 256 + t;        // n = id>>6, r = id&63  (coalesced over r)
            int n = id >> 6, r = id & 63;
            wct[(size_t)(half * 64 + n) * 4096 + kt * 64 + r] =
                __float2bfloat16(T[n][r]);
        }
    }
}

// ---------------- Stage 1: per-variable GRN + LN via bf16 MFMA -> stacked bf16
// wave = one variable x 32 tokens; grid (256 token-tiles, 16 var-groups), block 256.
__global__ __launch_bounds__(256) void vsn_stage1(
    const float* __restrict__ x,
    const float* __restrict__ W1, const float* __restrict__ b1,
    const short* __restrict__ w2b, const short* __restrict__ wgb,
    const float* __restrict__ b2, const float* __restrict__ bg,
    const float* __restrict__ Wsk, const float* __restrict__ bsk,
    const float* __restrict__ gamma, const float* __restrict__ beta,
    __hip_bfloat16* __restrict__ stb)
{
    const int t = threadIdx.x;
    const int wave = t >> 6, lane = t & 63;
    const int m16 = lane & 15, quad = lane >> 4;
    const int tile0 = blockIdx.x * 32;
    const int v = blockIdx.y * 4 + wave;

    __shared__ float xs[4][32];
    __shared__ __align__(16) unsigned short h2s[4][32][72];  // bf16 h2, per-wave

    if (lane < 32) xs[wave][lane] = x[(size_t)(tile0 + lane) * NV + v];
    // same-wave LDS RAW below: compiler inserts lgkmcnt; no barrier needed.

    // ---- h1 fragments: trunc-bf16, pair-packed
    s8v a[2][2];
    #pragma unroll
    for (int kt = 0; kt < 2; ++kt) {
        float w1k[8], b1k[8];
        *(float4*)&w1k[0] = *(const float4*)(W1 + v * 64 + kt * 32 + quad * 8);
        *(float4*)&w1k[4] = *(const float4*)(W1 + v * 64 + kt * 32 + quad * 8 + 4);
        *(float4*)&b1k[0] = *(const float4*)(b1 + v * 64 + kt * 32 + quad * 8);
        *(float4*)&b1k[4] = *(const float4*)(b1 + v * 64 + kt * 32 + quad * 8 + 4);
        #pragma unroll
        for (int mi = 0; mi < 2; ++mi) {
            float xv = xs[wave][mi * 16 + m16];
            float h[8];
            #pragma unroll
            for (int j = 0; j < 8; ++j) h[j] = elu_f(fmaf(xv, w1k[j], b1k[j]));
            i4v av;
            #pragma unroll
            for (int p = 0; p < 4; ++p) {
                unsigned int u0 = __float_as_uint(h[2 * p]);
                unsigned int u1 = __float_as_uint(h[2 * p + 1]);
                av[p] = (int)((u1 & 0xffff0000u) | (u0 >> 16));
            }
            a[mi][kt] = *(s8v*)&av;
        }
    }

    // ---- GEMM1: h2 = h1 @ W2_v + b2
    f4v hacc[2][4];
    #pragma unroll
    for (int mi = 0; mi < 2; ++mi)
        #pragma unroll
        for (int ni = 0; ni < 4; ++ni) hacc[mi][ni] = (f4v){0.f, 0.f, 0.f, 0.f};

    const size_t wb = (size_t)v * 4096;
    #pragma unroll
    for (int ni = 0; ni < 4; ++ni)
        #pragma unroll
        for (int kt = 0; kt < 2; ++kt) {
            s8v bh = *(const s8v*)(w2b + wb + (size_t)(ni * 16 + m16) * 64 + kt * 32 + quad * 8);
            #pragma unroll
            for (int mi = 0; mi < 2; ++mi)
                hacc[mi][ni] = __builtin_amdgcn_mfma_f32_16x16x32_bf16(a[mi][kt], bh, hacc[mi][ni], 0, 0, 0);
        }
    {
        float b2d[4];
        #pragma unroll
        for (int ni = 0; ni < 4; ++ni) b2d[ni] = b2[v * 64 + ni * 16 + m16];
        #pragma unroll
        for (int mi = 0; mi < 2; ++mi)
            #pragma unroll
            for (int ni = 0; ni < 4; ++ni)
                #pragma unroll
                for (int r = 0; r < 4; ++r) hacc[mi][ni][r] += b2d[ni];
    }

    // ---- h2: C-layout -> LDS (trunc hi16 store) -> A-layout fragments
    #pragma unroll
    for (int mi = 0; mi < 2; ++mi)
        #pragma unroll
        for (int ni = 0; ni < 4; ++ni)
            #pragma unroll
            for (int r = 0; r < 4; ++r)
                h2s[wave][mi * 16 + quad * 4 + r][ni * 16 + m16] =
                    (unsigned short)(__float_as_uint(hacc[mi][ni][r]) >> 16);

    s8v c[2][2];
    #pragma unroll
    for (int mi = 0; mi < 2; ++mi)
        #pragma unroll
        for (int kt = 0; kt < 2; ++kt)
            c[mi][kt] = *(const s8v*)&h2s[wave][mi * 16 + m16][kt * 32 + quad * 8];

    // ---- GEMM2: g = sigmoid(h2 @ Wg_v + bg)
    f4v gacc[2][4];
    #pragma unroll
    for (int mi = 0; mi < 2; ++mi)
        #pragma unroll
        for (int ni = 0; ni < 4; ++ni) gacc[mi][ni] = (f4v){0.f, 0.f, 0.f, 0.f};
    #pragma unroll
    for (int ni = 0; ni < 4; ++ni)
        #pragma unroll
        for (int kt = 0; kt < 2; ++kt) {
            s8v bh = *(const s8v*)(wgb + wb + (size_t)(ni * 16 + m16) * 64 + kt * 32 + quad * 8);
            #pragma unroll
            for (int mi = 0; mi < 2; ++mi)
                gacc[mi][ni] = __builtin_amdgcn_mfma_f32_16x16x32_bf16(c[mi][kt], bh, gacc[mi][ni], 0, 0, 0);
        }

    // ---- s = x*Wsk + bsk + sigm(g)*h2
    {
        float bgd[4], wskd[4], bskd[4];
        #pragma unroll
        for (int ni = 0; ni < 4; ++ni) {
            int d = v * 64 + ni * 16 + m16;
            bgd[ni] = bg[d]; wskd[ni] = Wsk[d]; bskd[ni] = bsk[d];
        }
        float xtok[2][4];
        #pragma unroll
        for (int mi = 0; mi < 2; ++mi)
            #pragma unroll
            for (int r = 0; r < 4; ++r) xtok[mi][r] = xs[wave][mi * 16 + quad * 4 + r];
        #pragma unroll
        for (int mi = 0; mi < 2; ++mi)
            #pragma unroll
            for (int ni = 0; ni < 4; ++ni)
                #pragma unroll
                for (int r = 0; r < 4; ++r) {
                    float g = sigm_f(gacc[mi][ni][r] + bgd[ni]);
                    gacc[mi][ni][r] = fmaf(xtok[mi][r], wskd[ni], bskd[ni]) + g * hacc[mi][ni][r];
                }
    }

    // ---- LayerNorm over d (16-lane shuffle) + bf16 store
    {
        float gamd[4], betd[4];
        #pragma unroll
        for (int ni = 0; ni < 4; ++ni) {
            int d = v * 64 + ni * 16 + m16;
            gamd[ni] = gamma[d]; betd[ni] = beta[d];
        }
        #pragma unroll
        for (int mi = 0; mi < 2; ++mi)
            #pragma unroll
            for (int r = 0; r < 4; ++r) {
                float s0 = gacc[mi][0][r], s1 = gacc[mi][1][r], s2 = gacc[mi][2][r], s3 = gacc[mi][3][r];
                float sum = s0 + s1 + s2 + s3;
                float sq  = s0 * s0 + s1 * s1 + s2 * s2 + s3 * s3;
                #pragma unroll
                for (int m = 1; m < 16; m <<= 1) { sum += __shfl_xor(sum, m); sq += __shfl_xor(sq, m); }
                float mu  = sum * 0.015625f;
                float var = sq * 0.015625f - mu * mu;
                float rs  = rsqrtf(var + LN_EPS);
                size_t base = (size_t)(tile0 + mi * 16 + quad * 4 + r) * 4096 + (size_t)v * 64 + m16;
                #pragma unroll
                for (int ni = 0; ni < 4; ++ni)
                    stb[base + ni * 16] = __hip_bfloat16_raw{
                        bf16_rn((gacc[mi][ni][r] - mu) * rs * gamd[ni] + betd[ni])};
            }
    }
}

// ---------------- Fused Stage 2: flat@[Wn1|Wns] (MFMA, in-block K-reduction)
// + tail GRN + LN/softmax + weighted sum. grid 256 blocks x 512 threads (8 waves).
// Wave w: n-half nh=w&1 (64 cols), K-slice ks=w>>1 (1024 wide). 32 tokens/block.
__global__ __launch_bounds__(512) void vsn_stage2(
    const __hip_bfloat16* __restrict__ stb,   // [8192][4096]
    const __hip_bfloat16* __restrict__ wct,   // [128][4096]
    const float* __restrict__ bn1,
    const float* __restrict__ Wn2, const float* __restrict__ bn2,
    const float* __restrict__ Wng, const float* __restrict__ bng,
    const float* __restrict__ bns,
    const float* __restrict__ ngamma, const float* __restrict__ nbeta,
    float* __restrict__ out)
{
    const int t = threadIdx.x;
    const int w = t >> 6, lane = t & 63;
    const int m16 = lane & 15, quad = lane >> 4;
    const int nh = w & 1, ks = w >> 1;
    const int tok0 = blockIdx.x * 32;

    // SM1: P[2][2][64][33] fp32 (33792 B); overlaid by hw1/skw/hw2 [32][64] each
    // SM2: S[32][132] fp32 (16896 B); overlaid by s2/wgt [32][64]
    __shared__ __align__(16) float SM1[2 * 2 * 64 * 33];
    __shared__ __align__(16) float SM2[32 * 132];
    float (*P)[2][64][33] = (float(*)[2][64][33])SM1;
    float (*hw1)[64] = (float(*)[64])SM1;
    float (*skw)[64] = (float(*)[64])(SM1 + 2048);
    float (*hw2)[64] = (float(*)[64])(SM1 + 4096);
    float (*S)[132]  = (float(*)[132])SM2;
    float (*s2m)[64] = (float(*)[64])SM2;
    float (*wgt)[64] = (float(*)[64])(SM2 + 2048);

    const short* A  = (const short*)stb;
    const short* Bw = (const short*)wct;
    const int k0 = ks * 1024;

    // ---- K-loop: partial C[32][nh*64..] over this wave's K-slice
    f4v acc[2][4];
    #pragma unroll
    for (int mi = 0; mi < 2; ++mi)
        #pragma unroll
        for (int nj = 0; nj < 4; ++nj) acc[mi][nj] = (f4v){0.f, 0.f, 0.f, 0.f};

    const short* arow = A  + (size_t)(tok0 + m16) * 4096 + k0 + quad * 8;
    const short* brow = Bw + (size_t)(nh * 64 + m16) * 4096 + k0 + quad * 8;

    #pragma unroll 4
    for (int kk = 0; kk < 1024; kk += 32) {
        s8v a0 = *(const s8v*)(arow + kk);
        s8v a1 = *(const s8v*)(arow + (size_t)16 * 4096 + kk);
        s8v b[4];
        #pragma unroll
        for (int nj = 0; nj < 4; ++nj)
            b[nj] = *(const s8v*)(brow + (size_t)nj * 16 * 4096 + kk);
        #pragma unroll
        for (int nj = 0; nj < 4; ++nj) {
            acc[0][nj] = __builtin_amdgcn_mfma_f32_16x16x32_bf16(a0, b[nj], acc[0][nj], 0, 0, 0);
            acc[1][nj] = __builtin_amdgcn_mfma_f32_16x16x32_bf16(a1, b[nj], acc[1][nj], 0, 0, 0);
        }
    }

    // ---- tree-reduce the 4 K-slices per n-half (stride-33: conflict-free)
    float* af = (float*)acc;     // 32 floats, same flatten for all waves
    if (ks >= 2) {
        float* p = &P[nh][ks - 2][lane][0];
        #pragma unroll
        for (int i = 0; i < 32; ++i) p[i] = af[i];
    }
    __syncthreads();
    if (ks < 2) {
        float* p = &P[nh][ks][lane][0];
        #pragma unroll
        for (int i = 0; i < 32; ++i) af[i] += p[i];
    }
    __syncthreads();
    if (ks == 1) {
        float* p = &P[nh][0][lane][0];
        #pragma unroll
        for (int i = 0; i < 32; ++i) p[i] = af[i];
    }
    __syncthreads();
    if (ks == 0) {
        float* p = &P[nh][0][lane][0];
        #pragma unroll
        for (int i = 0; i < 32; ++i) af[i] += p[i];
        #pragma unroll
        for (int mi = 0; mi < 2; ++mi)
            #pragma unroll
            for (int nj = 0; nj < 4; ++nj)
                #pragma unroll
                for (int r = 0; r < 4; ++r)
                    S[mi * 16 + quad * 4 + r][nh * 64 + nj * 16 + m16] = acc[mi][nj][r];
    }
    __syncthreads();

    // ---- tail step 1: hw1 = elu(S[:, :64]+bn1), skw = S[:, 64:]+bns
    #pragma unroll
    for (int i = 0; i < 4; ++i) {
        int id = i * 512 + t;
        int m = id >> 6, j = id & 63;
        hw1[m][j] = elu_f(S[m][j] + bn1[j]);
        skw[m][j] = S[m][64 + j] + bns[j];
    }
    __syncthreads();

    // ---- step 2: hw2 = hw1 @ Wn2 + bn2
    #pragma unroll
    for (int i = 0; i < 4; ++i) {
        int id = i * 512 + t;
        int m = id >> 6, j = id & 63;
        float a2 = bn2[j];
        #pragma unroll
        for (int k4 = 0; k4 < 16; ++k4) {
            float4 h = *(const float4*)&hw1[m][k4 * 4];
            a2 += h.x * Wn2[(k4*4+0)*64+j] + h.y * Wn2[(k4*4+1)*64+j]
                + h.z * Wn2[(k4*4+2)*64+j] + h.w * Wn2[(k4*4+3)*64+j];
        }
        hw2[m][j] = a2;
    }
    __syncthreads();

    // ---- step 3: gw = sigm(hw2 @ Wng + bng); s2 = skw + gw*hw2   (S dead now)
    #pragma unroll
    for (int i = 0; i < 4; ++i) {
        int id = i * 512 + t;
        int m = id >> 6, vv = id & 63;
        float a3 = bng[vv];
        #pragma unroll
        for (int k4 = 0; k4 < 16; ++k4) {
            float4 h = *(const float4*)&hw2[m][k4 * 4];
            a3 += h.x * Wng[(k4*4+0)*64+vv] + h.y * Wng[(k4*4+1)*64+vv]
                + h.z * Wng[(k4*4+2)*64+vv] + h.w * Wng[(k4*4+3)*64+vv];
        }
        float gw = sigm_f(a3);
        s2m[m][vv] = skw[m][vv] + gw * hw2[m][vv];
    }
    __syncthreads();

    // ---- step 4: LN over v + softmax; 512 threads = 32 tokens x 16 lanes
    {
        int tt = t >> 4, l = t & 15;
        float z[4]; float sum = 0.f, sq = 0.f;
        #pragma unroll
        for (int i = 0; i < 4; ++i) { z[i] = s2m[tt][l + 16 * i]; sum += z[i]; sq += z[i] * z[i]; }
        #pragma unroll
        for (int m = 1; m < 16; m <<= 1) { sum += __shfl_xor(sum, m); sq += __shfl_xor(sq, m); }
        float mu  = sum * 0.015625f;
        float var = sq * 0.015625f - mu * mu;
        float rs  = rsqrtf(var + LN_EPS);
        float ln[4]; float mx = -1e30f;
        #pragma unroll
        for (int i = 0; i < 4; ++i) {
            ln[i] = (z[i] - mu) * rs * ngamma[l + 16 * i] + nbeta[l + 16 * i];
            mx = fmaxf(mx, ln[i]);
        }
        #pragma unroll
        for (int m = 1; m < 16; m <<= 1) mx = fmaxf(mx, __shfl_xor(mx, m));
        float es = 0.f; float ev[4];
        #pragma unroll
        for (int i = 0; i < 4; ++i) { ev[i] = __expf(ln[i] - mx); es += ev[i]; }
        #pragma unroll
        for (int m = 1; m < 16; m <<= 1) es += __shfl_xor(es, m);
        float inv = 1.f / es;
        #pragma unroll
        for (int i = 0; i < 4; ++i) wgt[tt][l + 16 * i] = ev[i] * inv;
    }
    __syncthreads();

    // ---- step 5: weighted sum (stb rows are L2-warm from the K-loop)
    // wave w -> tokens tok0 + 4w .. 4w+3; per token: lanes (vloc, d8) read 1KB/iter.
    {
        const int vloc = lane >> 3, d8 = (lane & 7) * 8;
        #pragma unroll
        for (int tk = 0; tk < 4; ++tk) {
            int tl = w * 4 + tk;
            const short* sp = A + (size_t)(tok0 + tl) * 4096 + d8;
            float a8[8];
            #pragma unroll
            for (int j = 0; j < 8; ++j) a8[j] = 0.f;
            #pragma unroll
            for (int vc = 0; vc < 8; ++vc) {
                int v = vc * 8 + vloc;
                s8v r = *(const s8v*)(sp + v * 64);
                float wv = wgt[tl][v];
                #pragma unroll
                for (int j = 0; j < 8; ++j)
                    a8[j] = fmaf(wv, bf16_to_f((unsigned short)r[j]), a8[j]);
            }
            #pragma unroll
            for (int m = 8; m <= 32; m <<= 1)
                #pragma unroll
                for (int j = 0; j < 8; ++j) a8[j] += __shfl_xor(a8[j], m);
            if (lane < 8) {
                float* op = out + (size_t)(tok0 + tl) * 64 + lane * 8;
                *(float4*)op       = make_float4(a8[0], a8[1], a8[2], a8[3]);
                *(float4*)(op + 4) = make_float4(a8[4], a8[5], a8[6], a8[7]);
            }
        }
    }
}

extern "C" void kernel_launch(void* const* d_in, const int* in_sizes, int n_in,
                              void* d_out, int out_size, void* d_ws, size_t ws_size,
                              hipStream_t stream) {
    const float* x     = (const float*)d_in[0];
    const float* W1    = (const float*)d_in[1];
    const float* b1    = (const float*)d_in[2];
    const float* W2    = (const float*)d_in[3];
    const float* b2    = (const float*)d_in[4];
    const float* Wg    = (const float*)d_in[5];
    const float* bg    = (const float*)d_in[6];
    const float* Wsk   = (const float*)d_in[7];
    const float* bsk   = (const float*)d_in[8];
    const float* gamma = (const float*)d_in[9];
    const float* beta  = (const float*)d_in[10];
    const float* Wn1   = (const float*)d_in[11];
    const float* bn1   = (const float*)d_in[12];
    const float* Wn2   = (const float*)d_in[13];
    const float* bn2   = (const float*)d_in[14];
    const float* Wng   = (const float*)d_in[15];
    const float* bng   = (const float*)d_in[16];
    const float* Wns   = (const float*)d_in[17];
    const float* bns   = (const float*)d_in[18];
    const float* ngam  = (const float*)d_in[19];
    const float* nbet  = (const float*)d_in[20];

    char* ws = (char*)d_ws;
    __hip_bfloat16* stb = (__hip_bfloat16*)ws;                   // 64 MiB
    __hip_bfloat16* wct = (__hip_bfloat16*)(ws + (64u << 20));   // 1 MiB
    short* w2b = (short*)(ws + (65u << 20));                     // 512 KiB each
    short* wgb = w2b + 262144;
    float* outp = (float*)d_out;

    vsn_prepack<<<dim3(192), 256, 0, stream>>>(W2, Wg, Wn1, Wns, w2b, wgb, wct);
    vsn_stage1<<<dim3(NTOK / 32, 16), 256, 0, stream>>>(
        x, W1, b1, w2b, wgb, b2, bg, Wsk, bsk, gamma, beta, stb);
    vsn_stage2<<<dim3(NTOK / 32), 512, 0, stream>>>(
        stb, wct, bn1, Wn2, bn2, Wng, bng, bns, ngam, nbet, outp);
}